// Round 1
// baseline (331.321 us; speedup 1.0000x reference)
//
#include <hip/hip_runtime.h>
#include <cstdint>
#include <cstddef>

typedef __bf16 bf16;
typedef __attribute__((ext_vector_type(8))) __bf16 bf16x8;
typedef __attribute__((ext_vector_type(4))) __bf16 bf16x4;
typedef __attribute__((ext_vector_type(4))) float f32x4;

#define ADIM 1024
#define ASEQ 2048
#define ABATCH 8

__device__ __forceinline__ void gload_lds16(const void* g, void* l) {
  __builtin_amdgcn_global_load_lds(
      (const __attribute__((address_space(1))) void*)g,
      (__attribute__((address_space(3))) void*)l,
      16, 0, 0);
}

__device__ __forceinline__ f32x4 mfma16(bf16x8 a, bf16x8 b, f32x4 c) {
  return __builtin_amdgcn_mfma_f32_16x16x32_bf16(a, b, c, 0, 0, 0);
}

// ---------------- cast x (fp32 -> bf16), vectorized ----------------
__global__ void k_cast_x(const float* __restrict__ x, bf16* __restrict__ xb, int n4) {
  int i = blockIdx.x * blockDim.x + threadIdx.x;
  int stride = gridDim.x * blockDim.x;
  for (; i < n4; i += stride) {
    float4 f = ((const float4*)x)[i];
    bf16x4 o = { (bf16)f.x, (bf16)f.y, (bf16)f.z, (bf16)f.w };
    ((bf16x4*)xb)[i] = o;
  }
}

// ------------- weights: cast + transpose into B^T form -------------
// WcT[n][k] = W_{n>>10}[k][n&1023]  (n in [0,3072)), WoT[n][k] = Wo[k][n]
__global__ void k_prep_w(const float* __restrict__ Wq, const float* __restrict__ Wk,
                         const float* __restrict__ Wv, const float* __restrict__ Wo,
                         bf16* __restrict__ WcT, bf16* __restrict__ WoT) {
  int i = blockIdx.x * blockDim.x + threadIdx.x;
  int stride = gridDim.x * blockDim.x;
  const int NC = 3 * ADIM * ADIM;
  const int TOT = 4 * ADIM * ADIM;
  for (; i < TOT; i += stride) {
    if (i < NC) {
      int n = i >> 10, k = i & 1023;
      int cb = n >> 10, nn = n & 1023;
      const float* W = (cb == 0) ? Wq : (cb == 1) ? Wk : Wv;
      WcT[i] = (bf16)W[k * ADIM + nn];
    } else {
      int j = i - NC;
      int n = j >> 10, k = j & 1023;
      WoT[j] = (bf16)Wo[k * ADIM + n];
    }
  }
}

// --------------- B^T-form bf16 MFMA GEMM, 128x128 tile ---------------
// C[m][n] = sum_k A[m][k] * BT[n][k]
// MODE 0: N=3072 fused QKV epilogue -> Q bf16, K=elu+1 bf16, V transposed bf16 [B][D][S]
// MODE 1: out fp32 = C + bias0
template<int MODE>
__global__ __launch_bounds__(256) void k_gemm_bt(
    const bf16* __restrict__ A, const bf16* __restrict__ BT,
    const float* __restrict__ bias0, const float* __restrict__ bias1,
    const float* __restrict__ bias2,
    bf16* __restrict__ Qo, bf16* __restrict__ Ko, bf16* __restrict__ Vto,
    float* __restrict__ outF, int M, int N, int K)
{
  const int tid = threadIdx.x;
  const int l = tid & 63, w = tid >> 6;
  const int lr = l & 15, lk = (l >> 4) * 8;
  const int m0 = blockIdx.y * 128, n0 = blockIdx.x * 128;
  const int wr = (w >> 1) * 64, wc = (w & 1) * 64;

  __shared__ alignas(16) bf16 lA[2][128 * 32];
  __shared__ alignas(16) bf16 lB[2][128 * 32];

  f32x4 acc[4][4] = {};

  auto stage = [&](int buf, int k0) {
#pragma unroll
    for (int cc = 0; cc < 2; ++cc) {
      int c = 2 * w + cc;
      const bf16* ga = A + (size_t)(m0 + c * 16 + (l >> 2)) * K + k0 + (l & 3) * 8;
      gload_lds16(ga, &lA[buf][c * 16 * 32]);
      const bf16* gb = BT + (size_t)(n0 + c * 16 + (l >> 2)) * K + k0 + (l & 3) * 8;
      gload_lds16(gb, &lB[buf][c * 16 * 32]);
    }
  };

  stage(0, 0);
  __syncthreads();
  const int KT = K >> 5;
  for (int kt = 0; kt < KT; ++kt) {
    int cur = kt & 1;
    if (kt + 1 < KT) stage(cur ^ 1, (kt + 1) * 32);
    bf16x8 af[4], bfr[4];
#pragma unroll
    for (int i = 0; i < 4; ++i)
      af[i] = *(const bf16x8*)&lA[cur][(wr + i * 16 + lr) * 32 + lk];
#pragma unroll
    for (int j = 0; j < 4; ++j)
      bfr[j] = *(const bf16x8*)&lB[cur][(wc + j * 16 + lr) * 32 + lk];
#pragma unroll
    for (int i = 0; i < 4; ++i)
#pragma unroll
      for (int j = 0; j < 4; ++j)
        acc[i][j] = mfma16(af[i], bfr[j], acc[i][j]);
    __syncthreads();
  }

  const int er = (l >> 4) * 4, ec = l & 15;
#pragma unroll
  for (int i = 0; i < 4; ++i) {
#pragma unroll
    for (int j = 0; j < 4; ++j) {
#pragma unroll
      for (int r = 0; r < 4; ++r) {
        int m = m0 + wr + i * 16 + er + r;
        int n = n0 + wc + j * 16 + ec;
        float v = acc[i][j][r];
        if (MODE == 0) {
          int cb = n >> 10, nn = n & 1023;
          if (cb == 0) {
            v += bias0[nn];
            Qo[(size_t)m * ADIM + nn] = (bf16)v;
          } else if (cb == 1) {
            v += bias1[nn];
            float e = v > 0.f ? v + 1.f : __expf(v);   // elu(v)+1
            Ko[(size_t)m * ADIM + nn] = (bf16)e;
          } else {
            v += bias2[nn];
            int bb = m >> 11, t = m & 2047;            // m = b*SEQ + t
            Vto[((size_t)bb * ADIM + nn) * ASEQ + t] = (bf16)v;
          }
        } else {
          outF[(size_t)m * N + n] = v + bias0[n];
        }
      }
    }
  }
}

// --------- windowed decay attention: one (batch, 64-row q-tile) per WG ---------
// out[t][d] = sum_{s=t-64}^{t-1} decay^(t-1-s) (q_t . k_s) v_s[d]
__global__ __launch_bounds__(256) void k_attn(
    const bf16* __restrict__ Qg, const bf16* __restrict__ Kg,
    const bf16* __restrict__ Vt, bf16* __restrict__ Rb,
    const float* __restrict__ decay_param)
{
  const int b = blockIdx.y;
  const int T0 = blockIdx.x * 64;
  const int tid = threadIdx.x;
  const int l = tid & 63, w = tid >> 6;
  const int lr = l & 15, lk = (l >> 4) * 8;

  const float dp = decay_param[0];
  const float decay = 1.f / (1.f + __expf(-dp));
  const float l2d = __log2f(decay);

  __shared__ alignas(16) bf16 lQ[2][64 * 32];
  __shared__ alignas(16) bf16 lK[2][128 * 32];
  __shared__ alignas(16) bf16 lV[2][128 * 32];
  __shared__ alignas(16) bf16 lP[64 * 136];   // padded: 136*2B = 272B = 17*16B rows

  const bf16* Qb = Qg + (size_t)(b * ASEQ + T0) * ADIM;

  auto stageQK = [&](int buf, int k0) {
    {
      const bf16* g = Qb + (size_t)(w * 16 + (l >> 2)) * ADIM + k0 + (l & 3) * 8;
      gload_lds16(g, &lQ[buf][w * 16 * 32]);
    }
#pragma unroll
    for (int cc = 0; cc < 2; ++cc) {
      int c = 2 * w + cc;
      int sg = T0 - 64 + c * 16 + (l >> 2);
      if (sg < 0) sg = 0;                       // garbage keys get weight 0
      const bf16* g = Kg + (size_t)(b * ASEQ + sg) * ADIM + k0 + (l & 3) * 8;
      gload_lds16(g, &lK[buf][c * 16 * 32]);
    }
  };

  // ---- phase 1: S[64][128] = Q Kt over D=1024 ----
  f32x4 sc[4][2] = {};
  stageQK(0, 0);
  __syncthreads();
  for (int kt = 0; kt < 32; ++kt) {
    int cur = kt & 1;
    if (kt + 1 < 32) stageQK(cur ^ 1, (kt + 1) * 32);
    bf16x8 af[4], bfr[2];
#pragma unroll
    for (int i = 0; i < 4; ++i)
      af[i] = *(const bf16x8*)&lQ[cur][(i * 16 + lr) * 32 + lk];
#pragma unroll
    for (int j = 0; j < 2; ++j)
      bfr[j] = *(const bf16x8*)&lK[cur][(w * 32 + j * 16 + lr) * 32 + lk];
#pragma unroll
    for (int i = 0; i < 4; ++i)
#pragma unroll
      for (int j = 0; j < 2; ++j)
        sc[i][j] = mfma16(af[i], bfr[j], sc[i][j]);
    __syncthreads();
  }

  // ---- decay mask epilogue -> P (bf16) in LDS ----
  const int er = (l >> 4) * 4, ec = l & 15;
#pragma unroll
  for (int i = 0; i < 4; ++i)
#pragma unroll
    for (int j = 0; j < 2; ++j)
#pragma unroll
      for (int r = 0; r < 4; ++r) {
        int tl = i * 16 + er + r;
        int sl = w * 32 + j * 16 + ec;
        int sg = T0 - 64 + sl;
        int delta = (T0 + tl) - 1 - sg;
        float wgt = (delta >= 0 && delta < 64 && sg >= 0)
                        ? exp2f((float)delta * l2d) : 0.f;
        lP[tl * 136 + sl] = (bf16)(sc[i][j][r] * wgt);
      }

  // ---- phase 2: out[64][1024] = P V, V^T-form over s=128 ----
  auto stageV = [&](int buf, int g) {
    int nc = g >> 2, ks = g & 3;
#pragma unroll
    for (int cc = 0; cc < 2; ++cc) {
      int c = 2 * w + cc;
      int drow = nc * 128 + c * 16 + (l >> 2);
      int scol = T0 - 64 + ks * 32 + (l & 3) * 8;
      if (scol < 0) scol = 0;                   // garbage V gets P==0
      const bf16* gv = Vt + ((size_t)b * ADIM + drow) * ASEQ + scol;
      gload_lds16(gv, &lV[buf][c * 16 * 32]);
    }
  };

  f32x4 o[4][2] = {};
  stageV(0, 0);
  __syncthreads();   // covers lP writes + first V tile

  for (int g = 0; g < 32; ++g) {
    int cur = g & 1;
    if (g + 1 < 32) stageV(cur ^ 1, g + 1);
    int nc = g >> 2, ks = g & 3;
    bf16x8 af[4], bfr[2];
#pragma unroll
    for (int i = 0; i < 4; ++i)
      af[i] = *(const bf16x8*)&lP[(i * 16 + lr) * 136 + ks * 32 + lk];
#pragma unroll
    for (int j = 0; j < 2; ++j)
      bfr[j] = *(const bf16x8*)&lV[cur][(w * 32 + j * 16 + lr) * 32 + lk];
#pragma unroll
    for (int i = 0; i < 4; ++i)
#pragma unroll
      for (int j = 0; j < 2; ++j)
        o[i][j] = mfma16(af[i], bfr[j], o[i][j]);
    if (ks == 3) {
#pragma unroll
      for (int i = 0; i < 4; ++i)
#pragma unroll
        for (int j = 0; j < 2; ++j) {
#pragma unroll
          for (int r = 0; r < 4; ++r) {
            int tl = i * 16 + er + r;
            int dl = nc * 128 + w * 32 + j * 16 + ec;
            Rb[(size_t)(b * ASEQ + T0 + tl) * ADIM + dl] = (bf16)o[i][j][r];
          }
#pragma unroll
          for (int r = 0; r < 4; ++r) o[i][j][r] = 0.f;
        }
    }
    __syncthreads();
  }
}

extern "C" void kernel_launch(void* const* d_in, const int* in_sizes, int n_in,
                              void* d_out, int out_size, void* d_ws, size_t ws_size,
                              hipStream_t stream) {
  const float* x  = (const float*)d_in[0];
  const float* Wq = (const float*)d_in[1];
  const float* bq = (const float*)d_in[2];
  const float* Wk = (const float*)d_in[3];
  const float* bk = (const float*)d_in[4];
  const float* Wv = (const float*)d_in[5];
  const float* bv = (const float*)d_in[6];
  const float* Wo = (const float*)d_in[7];
  const float* bo = (const float*)d_in[8];
  const float* dp = (const float*)d_in[9];
  float* out = (float*)d_out;

  char* ws = (char*)d_ws;
  bf16* Xb  = (bf16*)(ws + ((size_t)0 << 20));    // 32 MB  [16384][1024]
  bf16* Qb  = (bf16*)(ws + ((size_t)32 << 20));   // 32 MB
  bf16* Kb  = (bf16*)(ws + ((size_t)64 << 20));   // 32 MB
  bf16* Vtb = (bf16*)(ws + ((size_t)96 << 20));   // 32 MB  [8][1024][2048]
  bf16* Rbb = (bf16*)(ws + ((size_t)128 << 20));  // 32 MB
  bf16* WcT = (bf16*)(ws + ((size_t)160 << 20));  // 6 MB   [3072][1024]
  bf16* WoT = (bf16*)(ws + ((size_t)166 << 20));  // 2 MB   [1024][1024]

  const int M = ABATCH * ASEQ;  // 16384

  k_cast_x<<<2048, 256, 0, stream>>>(x, Xb, (M * ADIM) / 4);
  k_prep_w<<<2048, 256, 0, stream>>>(Wq, Wk, Wv, Wo, WcT, WoT);
  k_gemm_bt<0><<<dim3(24, 128), 256, 0, stream>>>(
      Xb, WcT, bq, bk, bv, Qb, Kb, Vtb, nullptr, M, 3 * ADIM, ADIM);
  k_attn<<<dim3(32, 8), 256, 0, stream>>>(Qb, Kb, Vtb, Rbb, dp);
  k_gemm_bt<1><<<dim3(8, 128), 256, 0, stream>>>(
      Rbb, WoT, bo, nullptr, nullptr, nullptr, nullptr, nullptr, out, M, ADIM, ADIM);
}